// Round 8
// baseline (1387.991 us; speedup 1.0000x reference)
//
#include <hip/hip_runtime.h>
#include <hip/hip_bf16.h>
#include <cstdint>

// LGnet_mem v13: 2-deep stream ring + in-place permlane gate fold.
//   kprobe : detect fp32-vs-bf16 inputs; kconv: canonicalize weights to fp32.
//   k0a/k0b: fold weights  U = Wg1·(Wq3·Wfc)+Wg2, Wfold = Wg1·Wq12; swizzle frags.
//   Gc ping-pong; chunk 0 by standalone k2m; k3f = {WG 0..31 scan chunk c} +
//   {WG 32.. produce chunk c+1}; launch boundaries are the sync (v10 lesson).
//   v13a: stream ring st[3][3] (mod-3): slice kt+2 issued at kt; next step's
//         slices 0,1 issued in the gates phase -> 2-kt lookahead vs L2 ~250cy.
//   v13b: permlane32_swap folded into gate loop (sel[] removed, -16 VGPR,
//         pays for ring's +12). Bit-identical results.
//   Chunks {30,100,70} on big ws; TC=25/12 uniform fallback.
//   256-reg/wave cap at waves_per_eu(2,2) (v9 lesson) respected: net -4 regs.

typedef _Float16 half8  __attribute__((ext_vector_type(8)));
typedef _Float16 half4v __attribute__((ext_vector_type(4)));
typedef float    floatx4 __attribute__((ext_vector_type(4)));
typedef unsigned short ushort4v __attribute__((ext_vector_type(4)));

// ws layout (byte offsets)
#define OFF_FLAG   0x000000ULL
#define OFF_A32    0x001000ULL
#define OFF_BQ2    0x011000ULL
#define OFF_BFOLD  0x011400ULL
#define OFF_CAN    0x012400ULL
#define OFF_USW    0x1B0000ULL
#define OFF_WFSW   0x230000ULL
#define OFF_WFCSW  0x2B0000ULL
#define OFF_HST    0x2C0000ULL
#define OFF_CST    0x2E0000ULL
#define OFF_GC     0x320000ULL

// canonical weight offsets (fp32 elements)
#define CW_WZ   0
#define CW_BZ   16384
#define CW_WZP  16512
#define CW_BZP  32896
#define CW_WQ   33024
#define CW_BQ   57600
#define CW_WI   57664
#define CW_BI   139584
#define CW_WF   139840
#define CW_BF   221760
#define CW_WO   222016
#define CW_BO   303936
#define CW_WC   304192
#define CW_BC   386112
#define CW_WFC  386368
#define CW_BFC  419136

#define LGKM_BARRIER() asm volatile("s_waitcnt lgkmcnt(0)\n\ts_barrier" ::: "memory")

__device__ __forceinline__ float sigmoid_(float x) {
    return __builtin_amdgcn_rcpf(1.0f + __expf(-x));
}
__device__ __forceinline__ float tanh_(float x) {
    float e = __expf(2.0f * x);
    return 1.0f - 2.0f * __builtin_amdgcn_rcpf(e + 1.0f);
}
__device__ __forceinline__ float ldin(const void* p, size_t i, bool f32) {
    return f32 ? ((const float*)p)[i]
               : __bfloat162float(((const __hip_bfloat16*)p)[i]);
}
__device__ __forceinline__ floatx4 ldin4(const void* p, size_t i, bool f32) {
    floatx4 r;
    if (f32) {
        r = *(const floatx4*)((const float*)p + i);
    } else {
        ushort4v u = *(const ushort4v*)((const unsigned short*)p + i);
#pragma unroll
        for (int k = 0; k < 4; ++k) r[k] = __uint_as_float(((unsigned)u[k]) << 16);
    }
    return r;
}

// B-operand fragment swizzle for mfma_f32_16x16x32_f16:
// W[n][k] -> ((nt*8+kt)*64 + q*16 + (n&15))*8 + j   with k = kt*32+q*8+j
__device__ __forceinline__ int swz(int row, int k) {
    int nt = row >> 4, lr2 = row & 15;
    int kt = k >> 5, qq = (k >> 3) & 3, j = k & 7;
    return (((nt * 8 + kt) * 64) + (qq * 16 + lr2)) * 8 + j;
}

__global__ void kprobe(const void* __restrict__ wzraw, float* __restrict__ flag)
{
    __shared__ float red[256];
    int tid = threadIdx.x;
    const __hip_bfloat16* p = (const __hip_bfloat16*)wzraw;
    float mx = 0.f;
    for (int i = tid; i < 8192; i += 256) {
        float v = fabsf(__bfloat162float(p[2 * i]));
        if (!(v < 1e30f)) v = 1e30f;
        mx = fmaxf(mx, v);
    }
    red[tid] = mx;
    __syncthreads();
    for (int s = 128; s > 0; s >>= 1) {
        if (tid < s) red[tid] = fmaxf(red[tid], red[tid + s]);
        __syncthreads();
    }
    if (tid == 0) flag[0] = (red[0] > 1e4f) ? 1.0f : 0.0f;
}

__global__ void kconv(const float* __restrict__ flag,
                      const void* Wz,  const void* bz,  const void* Wzp, const void* bzp,
                      const void* Wq,  const void* bq,
                      const void* Wi,  const void* bi,  const void* Wf,  const void* bf,
                      const void* Wo,  const void* bo,  const void* Wc,  const void* bc,
                      const void* Wfc, const void* bfc,
                      float* __restrict__ can)
{
    const int sizes[16] = {16384,128,16384,128,24576,64,81920,256,81920,256,
                           81920,256,81920,256,32768,128};
    const int offs[16]  = {CW_WZ,CW_BZ,CW_WZP,CW_BZP,CW_WQ,CW_BQ,CW_WI,CW_BI,
                           CW_WF,CW_BF,CW_WO,CW_BO,CW_WC,CW_BC,CW_WFC,CW_BFC};
    const void* srcs[16] = {Wz,bz,Wzp,bzp,Wq,bq,Wi,bi,Wf,bf,Wo,bo,Wc,bc,Wfc,bfc};
    int aid = blockIdx.y;
    int i = blockIdx.x * 256 + threadIdx.x;
    if (i >= sizes[aid]) return;
    bool f32 = flag[0] > 0.5f;
    can[offs[aid] + i] = ldin(srcs[aid], i, f32);
}

__global__ void k0a(const float* __restrict__ can,
                    float* __restrict__ A32, float* __restrict__ bq2)
{
    int idx = blockIdx.x * 256 + threadIdx.x;
    if (idx < 16384) {
        int m = idx >> 8, k = idx & 255;
        float s = 0.f;
        for (int p = 0; p < 128; ++p)
            s += can[CW_WQ + m * 384 + 256 + p] * can[CW_WFC + p * 256 + k];
        A32[idx] = s;
    } else if (idx < 16448) {
        int m = idx - 16384;
        float s = can[CW_BQ + m];
        for (int p = 0; p < 128; ++p)
            s += can[CW_WQ + m * 384 + 256 + p] * can[CW_BFC + p];
        bq2[m] = s;
    }
}

__global__ void k0b(const float* __restrict__ can,
                    const float* __restrict__ A32, const float* __restrict__ bq2,
                    _Float16* __restrict__ U_sw, _Float16* __restrict__ Wf_sw,
                    _Float16* __restrict__ Wfc_sw, float* __restrict__ bfold)
{
    int blk = blockIdx.x, k = threadIdx.x;
    if (blk < 1024) {
        int g = blk >> 8, j = blk & 255;
        const float* Wg = can + (g == 0 ? CW_WI : g == 1 ? CW_WF : g == 2 ? CW_WO : CW_WC);
        const float* bg = can + (g == 0 ? CW_BI : g == 1 ? CW_BF : g == 2 ? CW_BO : CW_BC);
        float su = 0.f, sw = 0.f;
        for (int m = 0; m < 64; ++m) {
            float wgm = Wg[j * 320 + m];
            su += wgm * A32[m * 256 + k];
            sw += wgm * can[CW_WQ + m * 384 + k];
        }
        su += Wg[j * 320 + 64 + k];
        U_sw[swz(blk, k)]  = (_Float16)su;
        Wf_sw[swz(blk, k)] = (_Float16)sw;
        if (k == 0) {
            float sb = bg[j];
            for (int m = 0; m < 64; ++m)
                sb += Wg[j * 320 + m] * bq2[m];
            bfold[blk] = sb;
        }
    } else {
        int n = blk - 1024;
        Wfc_sw[swz(n, k)] = (_Float16)can[CW_WFC + n * 256 + k];
    }
}

// producer body: z/zp + GEMM for tile mt of a chunk starting at tbase.
// Gc layout: [tt][b>>3][1024][b&7] f16, tt local to chunk.
__device__ __forceinline__ void k2m_body(
    int mt, int tbase, bool f32, const void* __restrict__ inp,
    const void* __restrict__ xmean, const float* __restrict__ can,
    const _Float16* __restrict__ Wf_sw, const float* __restrict__ bfold,
    _Float16* __restrict__ Gc, _Float16* __restrict__ za)
{
    const int tt = mt >> 2;
    const int brow0 = (mt & 3) * 64;
    const int t = tbase + tt;
    const int tid = threadIdx.x;

    {   // phase 1: z/zp for 64 rows x 128 cols -> za
        int row = tid >> 3;
        int b = brow0 + row;
        int j16 = (tid & 7) * 16;
        size_t base  = ((size_t)b * 6 * 200 + t) * 128;
        size_t xbase = ((size_t)b * 200 + t) * 128;
        const int CS = 200 * 128;
#pragma unroll
        for (int c2 = 0; c2 < 4; ++c2) {
            int j = j16 + c2 * 4;
            floatx4 x   = ldin4(inp,   base + j, f32);
            floatx4 xl  = ldin4(inp,   base + CS + j, f32);
            floatx4 mk  = ldin4(inp,   base + 2 * CS + j, f32);
            floatx4 d   = ldin4(inp,   base + 3 * CS + j, f32);
            floatx4 xlb = ldin4(inp,   base + 4 * CS + j, f32);
            floatx4 db  = ldin4(inp,   base + 5 * CS + j, f32);
            floatx4 xm  = ldin4(xmean, xbase + j, f32);
#pragma unroll
            for (int u = 0; u < 4; ++u) {
                int jj = j + u;
                float dz  = __expf(-fmaxf(d[u]  * can[CW_WZ  + jj * 129] + can[CW_BZ  + jj], 0.f));
                float dzp = __expf(-fmaxf(db[u] * can[CW_WZP + jj * 129] + can[CW_BZP + jj], 0.f));
                float z  = mk[u] * x[u] + (1.f - mk[u]) * (dz  * xl[u]  + (1.f - dz)  * xm[u]);
                float zp = mk[u] * x[u] + (1.f - mk[u]) * (dzp * xlb[u] + (1.f - dzp) * xm[u]);
                za[row * 264 + jj]       = (_Float16)z;
                za[row * 264 + 128 + jj] = (_Float16)zp;
            }
        }
    }
    __syncthreads();

    // phase 2: GEMM za @ Wfold.T
    const int w = tid >> 6, L = tid & 63, q = L >> 4, lr = L & 15;
    const int row0 = (w & 3) * 16;
    const half8* __restrict__ Wb = (const half8*)Wf_sw;
    for (int nc = 0; nc < 4; ++nc) {
        const int nt0 = nc * 16 + (w >> 2) * 8;
        floatx4 acc[8];
#pragma unroll
        for (int i = 0; i < 8; ++i) {
            float bv = bfold[(nt0 + i) * 16 + lr];
            acc[i] = (floatx4){bv, bv, bv, bv};
        }
#pragma unroll
        for (int kt = 0; kt < 8; ++kt) {
            half8 a = *(const half8*)(&za[(row0 + lr) * 264 + kt * 32 + q * 8]);
#pragma unroll
            for (int i = 0; i < 8; ++i) {
                half8 b = Wb[(((nt0 + i) * 8) + kt) * 64 + L];
                acc[i] = __builtin_amdgcn_mfma_f32_16x16x32_f16(a, b, acc[i], 0, 0, 0);
            }
        }
        const int bg = brow0 + row0 + q * 4;
#pragma unroll
        for (int i = 0; i < 8; ++i) {
            int n = (nt0 + i) * 16 + lr;
            half4v pk;
#pragma unroll
            for (int r = 0; r < 4; ++r) pk[r] = (_Float16)acc[i][r];
            *(half4v*)(Gc + ((size_t)(tt * 32 + (bg >> 3)) * 1024 + n) * 8 + (bg & 7)) = pk;
        }
    }
}

// standalone producer for chunk 0
__global__ __launch_bounds__(512)
void k2m(int tbase, const float* __restrict__ flag,
         const void* __restrict__ inp, const void* __restrict__ xmean,
         const float* __restrict__ can, const _Float16* __restrict__ Wf_sw,
         const float* __restrict__ bfold, _Float16* __restrict__ Gc)
{
    __shared__ _Float16 za[64 * 264];
    k2m_body(blockIdx.x, tbase, flag[0] > 0.5f, inp, xmean, can, Wf_sw, bfold, Gc, za);
}

// fused: WG 0..31 = scan chunk (t0, ns steps) from gc_cur;
//        WG 32..  = producer tiles for next chunk (t0n) into gc_next.
__global__ void __launch_bounds__(512)
__attribute__((amdgpu_waves_per_eu(2, 2)))
k3f(int t0, int ns, int t0n, const float* __restrict__ flag,
    const _Float16* __restrict__ U_sw, const _Float16* __restrict__ Wfc_sw,
    const float* __restrict__ can, const _Float16* __restrict__ gc_cur,
    _Float16* __restrict__ gc_next,
    const void* __restrict__ inp, const void* __restrict__ xmean,
    const _Float16* __restrict__ Wf_sw, const float* __restrict__ bfold,
    _Float16* __restrict__ Hst, float* __restrict__ Cst,
    void* __restrict__ outv)
{
    __shared__ __align__(16) char smem[147968];   // max(h16+uldsv, za)
    const int tid = threadIdx.x;
    const bool f32m = flag[0] > 0.5f;

    if (blockIdx.x >= 32) {   // ---- producer path ----
        k2m_body(blockIdx.x - 32, t0n, f32m, inp, xmean, can, Wf_sw, bfold,
                 gc_next, (_Float16*)smem);
        return;
    }

    // ---- consumer path: serial scan ----
    const int wg = blockIdx.x;
    const int w = tid >> 6, L = tid & 63;
    const int q = L >> 4, lr = L & 15;
    const int qe = q & 1, us = q >> 1;   // mirror-lane fold: row-group, col-half

    _Float16* h16  = (_Float16*)smem;             // [2][16*264], 16896 B
    half8*    uldsv = (half8*)(smem + 16896);     // 16 tiles (o-gate), 131072 B

    // zero buf0 rows 8..15 and all of buf1; rows 8..15 are never written again.
    for (int i = tid; i < 8 * 264; i += 512)  h16[8 * 264 + i] = (_Float16)0.0f;
    for (int i = tid; i < 16 * 264; i += 512) h16[4224 + i] = (_Float16)0.0f;
    for (int i = tid; i < 8 * 256; i += 512) {
        int m = i >> 8, k = i & 255;
        h16[m * 264 + k] = Hst[(size_t)(wg * 8 + m) * 256 + k];
    }
    {   // one-time copy of o-gate tiles 32..47 into LDS (contiguous)
        const half8* __restrict__ Us8 = (const half8*)U_sw;
        for (int idx = tid; idx < 8192; idx += 512)
            uldsv[idx] = Us8[16384 + idx];
    }

    const half8* __restrict__ Ub = (const half8*)U_sw;
    const half8* __restrict__ Wb = (const half8*)Wfc_sw;

    half8 bp[4][8];                      // persistent i,f tiles (128 regs)
#pragma unroll
    for (int i = 0; i < 2; ++i)
#pragma unroll
        for (int kt = 0; kt < 8; ++kt) {
            bp[i][kt]     = Ub[(((w * 2 + i) * 8) + kt) * 64 + L];
            bp[2 + i][kt] = Ub[(((16 + w * 2 + i) * 8) + kt) * 64 + L];
        }

    // c-state: creg[r] = c[row wg*8+qe*4+r][col w*32+us*16+lr]  (all lanes real)
    float creg[4];
    {
        int row = wg * 8 + qe * 4;
#pragma unroll
        for (int r = 0; r < 4; ++r)
            creg[r] = Cst[(size_t)(row + r) * 256 + w * 32 + us * 16 + lr];
    }

    const float bfc_l = can[CW_BFC + w * 16 + lr];
    const _Float16* __restrict__ Gcb = gc_cur + (size_t)wg * 8192;
    __syncthreads();

    half4v gp[4];                        // G prefetch: 4 gates, per-lane (us,qe) slot

#define LOAD_G(ttx) do {                                                         \
    const _Float16* gsl = Gcb + (size_t)(ttx) * 262144;                          \
    _Pragma("unroll")                                                            \
    for (int g_ = 0; g_ < 4; ++g_)                                               \
        gp[g_] = __builtin_nontemporal_load(                                     \
            (const half4v*)(gsl + (((g_ * 16 + w * 2 + us) * 16 + lr) * 8) + qe * 4)); \
} while (0)

// issue stream slice kt=S into ring buffer st[(S)%3]
#define LOAD_ST(S) do {                                                          \
    _Pragma("unroll")                                                            \
    for (int j_ = 0; j_ < 2; ++j_)                                               \
        st[(S) % 3][j_] = __builtin_nontemporal_load(                            \
            &Ub[(((48 + w * 2 + j_) * 8) + (S)) * 64 + L]);                      \
    st[(S) % 3][2] = __builtin_nontemporal_load(&Wb[((w * 8) + (S)) * 64 + L]);  \
} while (0)

    LOAD_G(0);

    // stream ring st[3][3]: [0..1]=c-gate tiles 48+w*2+{0,1}; [2]=Wfc tile w.
    // mod-3 rotation, 2-kt lookahead: slice kt+2 issued at kt; slices 0,1 of the
    // next step issued during the gates phase (whole gates+barrier of lead time).
    half8 st[3][3];
    LOAD_ST(0);
    LOAD_ST(1);

#pragma unroll 1
    for (int tt = 0; tt < ns; ++tt) {
        const int p = tt & 1;
        const _Float16* __restrict__ hr = h16 + p * 4224;
        _Float16* __restrict__ hw = h16 + (p ^ 1) * 4224;

        floatx4 acc[8];
#pragma unroll
        for (int i = 0; i < 8; ++i) acc[i] = (floatx4){0.f, 0.f, 0.f, 0.f};
        floatx4 ao = (floatx4){bfc_l, bfc_l, bfc_l, bfc_l};

#pragma unroll
        for (int kt = 0; kt < 8; ++kt) {
            half8 a  = *(const half8*)(&hr[lr * 264 + kt * 32 + q * 8]);
            half8 u4 = uldsv[((w * 2 + 0) << 9) + (kt << 6) + L];
            half8 u5 = uldsv[((w * 2 + 1) << 9) + (kt << 6) + L];
            if (kt < 6) LOAD_ST(kt + 2);
#pragma unroll
            for (int i = 0; i < 4; ++i)
                acc[i] = __builtin_amdgcn_mfma_f32_16x16x32_f16(a, bp[i][kt], acc[i], 0, 0, 0);
            acc[4] = __builtin_amdgcn_mfma_f32_16x16x32_f16(a, u4, acc[4], 0, 0, 0);
            acc[5] = __builtin_amdgcn_mfma_f32_16x16x32_f16(a, u5, acc[5], 0, 0, 0);
            acc[6] = __builtin_amdgcn_mfma_f32_16x16x32_f16(a, st[kt % 3][0], acc[6], 0, 0, 0);
            acc[7] = __builtin_amdgcn_mfma_f32_16x16x32_f16(a, st[kt % 3][1], acc[7], 0, 0, 0);
            ao     = __builtin_amdgcn_mfma_f32_16x16x32_f16(a, st[kt % 3][2], ao, 0, 0, 0);
        }

        // issue next step's kt=0,1 stream slices: land across gates+barrier
        LOAD_ST(0);
        LOAD_ST(1);

        // store out(t-1) — K-loop above read h(t-1); ao is ready now
        int tprev = t0 + tt - 1;
        if (tprev >= 0 && q < 2) {
            int n = w * 16 + lr;
            if (f32m) {
                float* o32 = (float*)outv;
#pragma unroll
                for (int r = 0; r < 4; ++r)
                    o32[((size_t)(wg * 8 + q * 4 + r) * 200 + tprev) * 128 + n] = ao[r];
            } else {
                __hip_bfloat16* o16 = (__hip_bfloat16*)outv;
#pragma unroll
                for (int r = 0; r < 4; ++r)
                    o16[((size_t)(wg * 8 + q * 4 + r) * 200 + tprev) * 128 + n] = __float2bfloat16(ao[r]);
            }
        }

        // mirror-lane fold + fused gates + c/h update (in place, no sel array):
        // lanes>=32 receive real u=1 elements via v_permlane32_swap_b32.
        {
            const int colb = w * 32 + us * 16 + lr;
#pragma unroll
            for (int r = 0; r < 4; ++r) {
                float vg[4];
#pragma unroll
                for (int g = 0; g < 4; ++g) {
                    float a0 = acc[2 * g][r], a1 = acc[2 * g + 1][r];
                    asm("v_permlane32_swap_b32 %0, %1" : "+v"(a0), "+v"(a1));
                    vg[g] = a0;
                }
                float ii = sigmoid_(vg[0] + (float)gp[0][r]);
                float ff = sigmoid_(vg[1] + (float)gp[1][r]);
                float oo = sigmoid_(vg[2] + (float)gp[2][r]);
                float cc = tanh_  (vg[3] + (float)gp[3][r]);
                float c  = ff * creg[r] + ii * cc;
                creg[r] = c;
                hw[(qe * 4 + r) * 264 + colb] = (_Float16)(oo * tanh_(c));
            }
        }
        if (tt + 1 < ns) LOAD_G(tt + 1);   // refill for next step

        LGKM_BARRIER();   // drains h-writes; next step reads the other buffer
    }

    // final chunk: emit out(199) from h(199)
    if (t0 + ns >= 200) {
        const _Float16* __restrict__ hf = h16 + (ns & 1) * 4224;
        floatx4 ao = (floatx4){bfc_l, bfc_l, bfc_l, bfc_l};
#pragma unroll
        for (int kt = 0; kt < 8; ++kt) {
            half8 a = *(const half8*)(&hf[lr * 264 + kt * 32 + q * 8]);
            half8 b = Wb[((w * 8) + kt) * 64 + L];
            ao = __builtin_amdgcn_mfma_f32_16x16x32_f16(a, b, ao, 0, 0, 0);
        }
        if (q < 2) {
            int n = w * 16 + lr;
            if (f32m) {
                float* o32 = (float*)outv;
#pragma unroll
                for (int r = 0; r < 4; ++r)
                    o32[((size_t)(wg * 8 + q * 4 + r) * 200 + 199) * 128 + n] = ao[r];
            } else {
                __hip_bfloat16* o16 = (__hip_bfloat16*)outv;
#pragma unroll
                for (int r = 0; r < 4; ++r)
                    o16[((size_t)(wg * 8 + q * 4 + r) * 200 + 199) * 128 + n] = __float2bfloat16(ao[r]);
            }
        }
    }

    // save state (all lanes hold real, disjoint c patches)
    for (int i = tid; i < 8 * 256; i += 512) {
        int m = i >> 8, k = i & 255;
        Hst[(size_t)(wg * 8 + m) * 256 + k] = h16[(ns & 1) * 4224 + m * 264 + k];
    }
    {
        int row = wg * 8 + qe * 4;
#pragma unroll
        for (int r = 0; r < 4; ++r)
            Cst[(size_t)(row + r) * 256 + w * 32 + us * 16 + lr] = creg[r];
    }
#undef LOAD_G
#undef LOAD_ST
}

extern "C" void kernel_launch(void* const* d_in, const int* in_sizes, int n_in,
                              void* d_out, int out_size, void* d_ws, size_t ws_size,
                              hipStream_t stream)
{
    char* ws = (char*)d_ws;
    float*     flag   = (float*)(ws + OFF_FLAG);
    float*     A32    = (float*)(ws + OFF_A32);
    float*     bq2    = (float*)(ws + OFF_BQ2);
    float*     bfold  = (float*)(ws + OFF_BFOLD);
    float*     can    = (float*)(ws + OFF_CAN);
    _Float16*  U_sw   = (_Float16*)(ws + OFF_USW);
    _Float16*  Wf_sw  = (_Float16*)(ws + OFF_WFSW);
    _Float16*  Wfc_sw = (_Float16*)(ws + OFF_WFCSW);
    _Float16*  Hst    = (_Float16*)(ws + OFF_HST);
    float*     Cst    = (float*)(ws + OFF_CST);

    // chunk schedule on ws_size: big ws -> asymmetric {30,100,70} (small chunk-0
    // producer); else uniform TC=25 / TC=12 tiers.
    int t0s[20], nss[20], nch, gcsz;
    if (ws_size >= OFF_GC + 2ULL * 100 * 524288ULL) {
        nch = 3; gcsz = 100;
        t0s[0] = 0;  nss[0] = 30;
        t0s[1] = 30; nss[1] = 100;
        t0s[2] = 130; nss[2] = 70;
    } else {
        int TC = (ws_size >= OFF_GC + 2ULL * 25 * 524288ULL) ? 25 : 12;
        gcsz = TC; nch = 0;
        for (int t0 = 0; t0 < 200; t0 += TC) {
            t0s[nch] = t0;
            nss[nch] = (200 - t0 < TC) ? (200 - t0) : TC;
            ++nch;
        }
    }
    _Float16* Gcb0 = (_Float16*)(ws + OFF_GC);
    _Float16* Gcb1 = Gcb0 + (size_t)gcsz * 262144;

    hipMemsetAsync(ws + OFF_HST, 0, 0x60000, stream);   // zero h,c state
    kprobe<<<1, 256, 0, stream>>>(d_in[2], flag);
    kconv<<<dim3(320, 16), 256, 0, stream>>>(flag,
        d_in[2], d_in[3], d_in[4], d_in[5], d_in[6], d_in[7],
        d_in[8], d_in[9], d_in[10], d_in[11], d_in[12], d_in[13],
        d_in[14], d_in[15], d_in[16], d_in[17], can);
    k0a<<<65, 256, 0, stream>>>(can, A32, bq2);
    k0b<<<1152, 256, 0, stream>>>(can, A32, bq2, U_sw, Wf_sw, Wfc_sw, bfold);

    // chunk 0 producer (standalone, small)
    k2m<<<4 * nss[0], 512, 0, stream>>>(t0s[0], flag, d_in[0], d_in[1], can,
                                        Wf_sw, bfold, Gcb0);

    for (int c = 0; c < nch; ++c) {
        int nsn = (c + 1 < nch) ? nss[c + 1] : 0;
        int t0n = (c + 1 < nch) ? t0s[c + 1] : 0;
        _Float16* gcur  = (c & 1) ? Gcb1 : Gcb0;
        _Float16* gnext = (c & 1) ? Gcb0 : Gcb1;
        k3f<<<32 + 4 * nsn, 512, 0, stream>>>(t0s[c], nss[c], t0n, flag, U_sw,
            Wfc_sw, can, gcur, gnext, d_in[0], d_in[1], Wf_sw, bfold,
            Hst, Cst, d_out);
    }
}

// Round 9
// 983.880 us; speedup vs baseline: 1.4107x; 1.4107x over previous
//
#include <hip/hip_runtime.h>
#include <hip/hip_bf16.h>
#include <cstdint>

// LGnet_mem v14: v12 base (ring reverted to 2-slot) + deferred output projection.
//   kprobe : detect fp32-vs-bf16 inputs; kconv: canonicalize weights to fp32.
//   k0a/k0b: fold weights  U = Wg1·(Wq3·Wfc)+Wg2, Wfold = Wg1·Wq12; swizzle frags.
//   Gc ping-pong; chunk 0 by standalone k2m; k3f<DEFER> = {WG 0..31 scan} +
//   {WG 32.. produce next chunk}; launch boundaries are the sync (v10 lesson).
//   v14: out(t) = h(t)@Wfc^T + bfc is NOT part of the recurrence (its feedback
//   is folded into U) -> remove ao-MFMA/Wfc-stream/out-store from the serial
//   step; scan streams h(t) to Hall[200][256][256] f16; trailing kout kernel
//   (200 WGs, h[t] in LDS, Wfc in regs) computes all outputs in parallel.
//   Bit-identical (h already passed through f16). Falls back to exact v12
//   path (k3f<false>) when ws has no room for Hall.
//   v13 lesson: stream lookahead >1 kt hurts — ring is 2-slot.
//   v9 lesson: 256 regs/wave cap at waves_per_eu(2,2) — DEFER path ~230.

typedef _Float16 half8  __attribute__((ext_vector_type(8)));
typedef _Float16 half4v __attribute__((ext_vector_type(4)));
typedef float    floatx4 __attribute__((ext_vector_type(4)));
typedef unsigned short ushort4v __attribute__((ext_vector_type(4)));

// ws layout (byte offsets)
#define OFF_FLAG   0x000000ULL
#define OFF_A32    0x001000ULL
#define OFF_BQ2    0x011000ULL
#define OFF_BFOLD  0x011400ULL
#define OFF_CAN    0x012400ULL
#define OFF_USW    0x1B0000ULL
#define OFF_WFSW   0x230000ULL
#define OFF_WFCSW  0x2B0000ULL
#define OFF_HST    0x2C0000ULL
#define OFF_CST    0x2E0000ULL
#define OFF_GC     0x320000ULL

// canonical weight offsets (fp32 elements)
#define CW_WZ   0
#define CW_BZ   16384
#define CW_WZP  16512
#define CW_BZP  32896
#define CW_WQ   33024
#define CW_BQ   57600
#define CW_WI   57664
#define CW_BI   139584
#define CW_WF   139840
#define CW_BF   221760
#define CW_WO   222016
#define CW_BO   303936
#define CW_WC   304192
#define CW_BC   386112
#define CW_WFC  386368
#define CW_BFC  419136

#define LGKM_BARRIER() asm volatile("s_waitcnt lgkmcnt(0)\n\ts_barrier" ::: "memory")

__device__ __forceinline__ float sigmoid_(float x) {
    return __builtin_amdgcn_rcpf(1.0f + __expf(-x));
}
__device__ __forceinline__ float tanh_(float x) {
    float e = __expf(2.0f * x);
    return 1.0f - 2.0f * __builtin_amdgcn_rcpf(e + 1.0f);
}
__device__ __forceinline__ float ldin(const void* p, size_t i, bool f32) {
    return f32 ? ((const float*)p)[i]
               : __bfloat162float(((const __hip_bfloat16*)p)[i]);
}
__device__ __forceinline__ floatx4 ldin4(const void* p, size_t i, bool f32) {
    floatx4 r;
    if (f32) {
        r = *(const floatx4*)((const float*)p + i);
    } else {
        ushort4v u = *(const ushort4v*)((const unsigned short*)p + i);
#pragma unroll
        for (int k = 0; k < 4; ++k) r[k] = __uint_as_float(((unsigned)u[k]) << 16);
    }
    return r;
}

// B-operand fragment swizzle for mfma_f32_16x16x32_f16:
// W[n][k] -> ((nt*8+kt)*64 + q*16 + (n&15))*8 + j   with k = kt*32+q*8+j
__device__ __forceinline__ int swz(int row, int k) {
    int nt = row >> 4, lr2 = row & 15;
    int kt = k >> 5, qq = (k >> 3) & 3, j = k & 7;
    return (((nt * 8 + kt) * 64) + (qq * 16 + lr2)) * 8 + j;
}

__global__ void kprobe(const void* __restrict__ wzraw, float* __restrict__ flag)
{
    __shared__ float red[256];
    int tid = threadIdx.x;
    const __hip_bfloat16* p = (const __hip_bfloat16*)wzraw;
    float mx = 0.f;
    for (int i = tid; i < 8192; i += 256) {
        float v = fabsf(__bfloat162float(p[2 * i]));
        if (!(v < 1e30f)) v = 1e30f;
        mx = fmaxf(mx, v);
    }
    red[tid] = mx;
    __syncthreads();
    for (int s = 128; s > 0; s >>= 1) {
        if (tid < s) red[tid] = fmaxf(red[tid], red[tid + s]);
        __syncthreads();
    }
    if (tid == 0) flag[0] = (red[0] > 1e4f) ? 1.0f : 0.0f;
}

__global__ void kconv(const float* __restrict__ flag,
                      const void* Wz,  const void* bz,  const void* Wzp, const void* bzp,
                      const void* Wq,  const void* bq,
                      const void* Wi,  const void* bi,  const void* Wf,  const void* bf,
                      const void* Wo,  const void* bo,  const void* Wc,  const void* bc,
                      const void* Wfc, const void* bfc,
                      float* __restrict__ can)
{
    const int sizes[16] = {16384,128,16384,128,24576,64,81920,256,81920,256,
                           81920,256,81920,256,32768,128};
    const int offs[16]  = {CW_WZ,CW_BZ,CW_WZP,CW_BZP,CW_WQ,CW_BQ,CW_WI,CW_BI,
                           CW_WF,CW_BF,CW_WO,CW_BO,CW_WC,CW_BC,CW_WFC,CW_BFC};
    const void* srcs[16] = {Wz,bz,Wzp,bzp,Wq,bq,Wi,bi,Wf,bf,Wo,bo,Wc,bc,Wfc,bfc};
    int aid = blockIdx.y;
    int i = blockIdx.x * 256 + threadIdx.x;
    if (i >= sizes[aid]) return;
    bool f32 = flag[0] > 0.5f;
    can[offs[aid] + i] = ldin(srcs[aid], i, f32);
}

__global__ void k0a(const float* __restrict__ can,
                    float* __restrict__ A32, float* __restrict__ bq2)
{
    int idx = blockIdx.x * 256 + threadIdx.x;
    if (idx < 16384) {
        int m = idx >> 8, k = idx & 255;
        float s = 0.f;
        for (int p = 0; p < 128; ++p)
            s += can[CW_WQ + m * 384 + 256 + p] * can[CW_WFC + p * 256 + k];
        A32[idx] = s;
    } else if (idx < 16448) {
        int m = idx - 16384;
        float s = can[CW_BQ + m];
        for (int p = 0; p < 128; ++p)
            s += can[CW_WQ + m * 384 + 256 + p] * can[CW_BFC + p];
        bq2[m] = s;
    }
}

__global__ void k0b(const float* __restrict__ can,
                    const float* __restrict__ A32, const float* __restrict__ bq2,
                    _Float16* __restrict__ U_sw, _Float16* __restrict__ Wf_sw,
                    _Float16* __restrict__ Wfc_sw, float* __restrict__ bfold)
{
    int blk = blockIdx.x, k = threadIdx.x;
    if (blk < 1024) {
        int g = blk >> 8, j = blk & 255;
        const float* Wg = can + (g == 0 ? CW_WI : g == 1 ? CW_WF : g == 2 ? CW_WO : CW_WC);
        const float* bg = can + (g == 0 ? CW_BI : g == 1 ? CW_BF : g == 2 ? CW_BO : CW_BC);
        float su = 0.f, sw = 0.f;
        for (int m = 0; m < 64; ++m) {
            float wgm = Wg[j * 320 + m];
            su += wgm * A32[m * 256 + k];
            sw += wgm * can[CW_WQ + m * 384 + k];
        }
        su += Wg[j * 320 + 64 + k];
        U_sw[swz(blk, k)]  = (_Float16)su;
        Wf_sw[swz(blk, k)] = (_Float16)sw;
        if (k == 0) {
            float sb = bg[j];
            for (int m = 0; m < 64; ++m)
                sb += Wg[j * 320 + m] * bq2[m];
            bfold[blk] = sb;
        }
    } else {
        int n = blk - 1024;
        Wfc_sw[swz(n, k)] = (_Float16)can[CW_WFC + n * 256 + k];
    }
}

// producer body: z/zp + GEMM for tile mt of a chunk starting at tbase.
// Gc layout: [tt][b>>3][1024][b&7] f16, tt local to chunk.
__device__ __forceinline__ void k2m_body(
    int mt, int tbase, bool f32, const void* __restrict__ inp,
    const void* __restrict__ xmean, const float* __restrict__ can,
    const _Float16* __restrict__ Wf_sw, const float* __restrict__ bfold,
    _Float16* __restrict__ Gc, _Float16* __restrict__ za)
{
    const int tt = mt >> 2;
    const int brow0 = (mt & 3) * 64;
    const int t = tbase + tt;
    const int tid = threadIdx.x;

    {   // phase 1: z/zp for 64 rows x 128 cols -> za
        int row = tid >> 3;
        int b = brow0 + row;
        int j16 = (tid & 7) * 16;
        size_t base  = ((size_t)b * 6 * 200 + t) * 128;
        size_t xbase = ((size_t)b * 200 + t) * 128;
        const int CS = 200 * 128;
#pragma unroll
        for (int c2 = 0; c2 < 4; ++c2) {
            int j = j16 + c2 * 4;
            floatx4 x   = ldin4(inp,   base + j, f32);
            floatx4 xl  = ldin4(inp,   base + CS + j, f32);
            floatx4 mk  = ldin4(inp,   base + 2 * CS + j, f32);
            floatx4 d   = ldin4(inp,   base + 3 * CS + j, f32);
            floatx4 xlb = ldin4(inp,   base + 4 * CS + j, f32);
            floatx4 db  = ldin4(inp,   base + 5 * CS + j, f32);
            floatx4 xm  = ldin4(xmean, xbase + j, f32);
#pragma unroll
            for (int u = 0; u < 4; ++u) {
                int jj = j + u;
                float dz  = __expf(-fmaxf(d[u]  * can[CW_WZ  + jj * 129] + can[CW_BZ  + jj], 0.f));
                float dzp = __expf(-fmaxf(db[u] * can[CW_WZP + jj * 129] + can[CW_BZP + jj], 0.f));
                float z  = mk[u] * x[u] + (1.f - mk[u]) * (dz  * xl[u]  + (1.f - dz)  * xm[u]);
                float zp = mk[u] * x[u] + (1.f - mk[u]) * (dzp * xlb[u] + (1.f - dzp) * xm[u]);
                za[row * 264 + jj]       = (_Float16)z;
                za[row * 264 + 128 + jj] = (_Float16)zp;
            }
        }
    }
    __syncthreads();

    // phase 2: GEMM za @ Wfold.T
    const int w = tid >> 6, L = tid & 63, q = L >> 4, lr = L & 15;
    const int row0 = (w & 3) * 16;
    const half8* __restrict__ Wb = (const half8*)Wf_sw;
    for (int nc = 0; nc < 4; ++nc) {
        const int nt0 = nc * 16 + (w >> 2) * 8;
        floatx4 acc[8];
#pragma unroll
        for (int i = 0; i < 8; ++i) {
            float bv = bfold[(nt0 + i) * 16 + lr];
            acc[i] = (floatx4){bv, bv, bv, bv};
        }
#pragma unroll
        for (int kt = 0; kt < 8; ++kt) {
            half8 a = *(const half8*)(&za[(row0 + lr) * 264 + kt * 32 + q * 8]);
#pragma unroll
            for (int i = 0; i < 8; ++i) {
                half8 b = Wb[(((nt0 + i) * 8) + kt) * 64 + L];
                acc[i] = __builtin_amdgcn_mfma_f32_16x16x32_f16(a, b, acc[i], 0, 0, 0);
            }
        }
        const int bg = brow0 + row0 + q * 4;
#pragma unroll
        for (int i = 0; i < 8; ++i) {
            int n = (nt0 + i) * 16 + lr;
            half4v pk;
#pragma unroll
            for (int r = 0; r < 4; ++r) pk[r] = (_Float16)acc[i][r];
            *(half4v*)(Gc + ((size_t)(tt * 32 + (bg >> 3)) * 1024 + n) * 8 + (bg & 7)) = pk;
        }
    }
}

// standalone producer for chunk 0
__global__ __launch_bounds__(512)
void k2m(int tbase, const float* __restrict__ flag,
         const void* __restrict__ inp, const void* __restrict__ xmean,
         const float* __restrict__ can, const _Float16* __restrict__ Wf_sw,
         const float* __restrict__ bfold, _Float16* __restrict__ Gc)
{
    __shared__ _Float16 za[64 * 264];
    k2m_body(blockIdx.x, tbase, flag[0] > 0.5f, inp, xmean, can, Wf_sw, bfold, Gc, za);
}

// fused: WG 0..31 = scan chunk (t0, ns steps) from gc_cur;
//        WG 32..  = producer tiles for next chunk (t0n) into gc_next.
// DEFER=true: no ao/out in the scan; h(t) streamed to hall.
template<bool DEFER>
__global__ void __launch_bounds__(512)
__attribute__((amdgpu_waves_per_eu(2, 2)))
k3f(int t0, int ns, int t0n, const float* __restrict__ flag,
    const _Float16* __restrict__ U_sw, const _Float16* __restrict__ Wfc_sw,
    const float* __restrict__ can, const _Float16* __restrict__ gc_cur,
    _Float16* __restrict__ gc_next,
    const void* __restrict__ inp, const void* __restrict__ xmean,
    const _Float16* __restrict__ Wf_sw, const float* __restrict__ bfold,
    _Float16* __restrict__ Hst, float* __restrict__ Cst,
    _Float16* __restrict__ hall, void* __restrict__ outv)
{
    __shared__ __align__(16) char smem[147968];   // max(h16+uldsv, za)
    const int tid = threadIdx.x;
    const bool f32m = flag[0] > 0.5f;

    if (blockIdx.x >= 32) {   // ---- producer path ----
        k2m_body(blockIdx.x - 32, t0n, f32m, inp, xmean, can, Wf_sw, bfold,
                 gc_next, (_Float16*)smem);
        return;
    }

    // ---- consumer path: serial scan ----
    const int wg = blockIdx.x;
    const int w = tid >> 6, L = tid & 63;
    const int q = L >> 4, lr = L & 15;
    const int qe = q & 1, us = q >> 1;   // mirror-lane fold: row-group, col-half

    _Float16* h16  = (_Float16*)smem;             // [2][16*264], 16896 B
    half8*    uldsv = (half8*)(smem + 16896);     // 16 tiles (o-gate), 131072 B

    for (int i = tid; i < 8 * 264; i += 512)  h16[8 * 264 + i] = (_Float16)0.0f;
    for (int i = tid; i < 16 * 264; i += 512) h16[4224 + i] = (_Float16)0.0f;
    for (int i = tid; i < 8 * 256; i += 512) {
        int m = i >> 8, k = i & 255;
        h16[m * 264 + k] = Hst[(size_t)(wg * 8 + m) * 256 + k];
    }
    {   // one-time copy of o-gate tiles 32..47 into LDS (contiguous)
        const half8* __restrict__ Us8 = (const half8*)U_sw;
        for (int idx = tid; idx < 8192; idx += 512)
            uldsv[idx] = Us8[16384 + idx];
    }

    const half8* __restrict__ Ub = (const half8*)U_sw;
    const half8* __restrict__ Wb = (const half8*)Wfc_sw;

    half8 bp[4][8];                      // persistent i,f tiles (128 regs)
#pragma unroll
    for (int i = 0; i < 2; ++i)
#pragma unroll
        for (int kt = 0; kt < 8; ++kt) {
            bp[i][kt]     = Ub[(((w * 2 + i) * 8) + kt) * 64 + L];
            bp[2 + i][kt] = Ub[(((16 + w * 2 + i) * 8) + kt) * 64 + L];
        }

    // c-state: creg[r] = c[row wg*8+qe*4+r][col w*32+us*16+lr]  (all lanes real)
    float creg[4];
    {
        int row = wg * 8 + qe * 4;
#pragma unroll
        for (int r = 0; r < 4; ++r)
            creg[r] = Cst[(size_t)(row + r) * 256 + w * 32 + us * 16 + lr];
    }

    const float bfc_l = can[CW_BFC + w * 16 + lr];
    const _Float16* __restrict__ Gcb = gc_cur + (size_t)wg * 8192;
    __syncthreads();

    half4v gp[4];                        // G prefetch: 4 gates, per-lane (us,qe) slot

#define LOAD_G(ttx) do {                                                         \
    const _Float16* gsl = Gcb + (size_t)(ttx) * 262144;                          \
    _Pragma("unroll")                                                            \
    for (int g_ = 0; g_ < 4; ++g_)                                               \
        gp[g_] = __builtin_nontemporal_load(                                     \
            (const half4v*)(gsl + (((g_ * 16 + w * 2 + us) * 16 + lr) * 8) + qe * 4)); \
} while (0)

    LOAD_G(0);

    // stream ring st[2][3]: [0..1]=c-gate tiles 48+w*2+{0,1}; [2]=Wfc tile w
    // (Wfc slot only in the !DEFER path). 2-slot (v13 lesson: deeper hurts).
    half8 st[2][3];
#pragma unroll
    for (int j = 0; j < 2; ++j)
        st[0][j] = __builtin_nontemporal_load(&Ub[(((48 + w * 2 + j) * 8) + 0) * 64 + L]);
    if constexpr (!DEFER)
        st[0][2] = __builtin_nontemporal_load(&Wb[((w * 8) + 0) * 64 + L]);

#pragma unroll 1
    for (int tt = 0; tt < ns; ++tt) {
        const int p = tt & 1;
        const _Float16* __restrict__ hr = h16 + p * 4224;
        _Float16* __restrict__ hw = h16 + (p ^ 1) * 4224;

        floatx4 acc[8];
#pragma unroll
        for (int i = 0; i < 8; ++i) acc[i] = (floatx4){0.f, 0.f, 0.f, 0.f};
        floatx4 ao;
        if constexpr (!DEFER) ao = (floatx4){bfc_l, bfc_l, bfc_l, bfc_l};

#pragma unroll
        for (int kt = 0; kt < 8; ++kt) {
            half8 a  = *(const half8*)(&hr[lr * 264 + kt * 32 + q * 8]);
            half8 u4 = uldsv[((w * 2 + 0) << 9) + (kt << 6) + L];
            half8 u5 = uldsv[((w * 2 + 1) << 9) + (kt << 6) + L];
            if (kt < 7) {
#pragma unroll
                for (int j = 0; j < 2; ++j)
                    st[(kt + 1) & 1][j] = __builtin_nontemporal_load(
                        &Ub[(((48 + w * 2 + j) * 8) + kt + 1) * 64 + L]);
                if constexpr (!DEFER)
                    st[(kt + 1) & 1][2] = __builtin_nontemporal_load(
                        &Wb[((w * 8) + kt + 1) * 64 + L]);
            }
#pragma unroll
            for (int i = 0; i < 4; ++i)
                acc[i] = __builtin_amdgcn_mfma_f32_16x16x32_f16(a, bp[i][kt], acc[i], 0, 0, 0);
            acc[4] = __builtin_amdgcn_mfma_f32_16x16x32_f16(a, u4, acc[4], 0, 0, 0);
            acc[5] = __builtin_amdgcn_mfma_f32_16x16x32_f16(a, u5, acc[5], 0, 0, 0);
            acc[6] = __builtin_amdgcn_mfma_f32_16x16x32_f16(a, st[kt & 1][0], acc[6], 0, 0, 0);
            acc[7] = __builtin_amdgcn_mfma_f32_16x16x32_f16(a, st[kt & 1][1], acc[7], 0, 0, 0);
            if constexpr (!DEFER)
                ao = __builtin_amdgcn_mfma_f32_16x16x32_f16(a, st[kt & 1][2], ao, 0, 0, 0);
        }

        // issue next step's kt=0 stream slice now: lands across gates+barrier
        if (tt + 1 < ns) {
#pragma unroll
            for (int j = 0; j < 2; ++j)
                st[0][j] = __builtin_nontemporal_load(&Ub[(((48 + w * 2 + j) * 8) + 0) * 64 + L]);
            if constexpr (!DEFER)
                st[0][2] = __builtin_nontemporal_load(&Wb[((w * 8) + 0) * 64 + L]);
        }

        // mirror-lane fold + fused gates + c/h update; write h(t) to hw (LDS)
        // and, in DEFER mode, stream h(t) to hall (fire-and-forget).
        {
            const int colb = w * 32 + us * 16 + lr;
#pragma unroll
            for (int r = 0; r < 4; ++r) {
                float vg[4];
#pragma unroll
                for (int g = 0; g < 4; ++g) {
                    float a0 = acc[2 * g][r], a1 = acc[2 * g + 1][r];
                    asm("v_permlane32_swap_b32 %0, %1" : "+v"(a0), "+v"(a1));
                    vg[g] = a0;
                }
                float ii = sigmoid_(vg[0] + (float)gp[0][r]);
                float ff = sigmoid_(vg[1] + (float)gp[1][r]);
                float oo = sigmoid_(vg[2] + (float)gp[2][r]);
                float cc = tanh_  (vg[3] + (float)gp[3][r]);
                float c  = ff * creg[r] + ii * cc;
                creg[r] = c;
                _Float16 hv = (_Float16)(oo * tanh_(c));
                hw[(qe * 4 + r) * 264 + colb] = hv;
                if constexpr (DEFER) {
                    __builtin_nontemporal_store(hv,
                        hall + ((size_t)(t0 + tt) * 256 + wg * 8 + qe * 4 + r) * 256 + colb);
                }
            }
        }
        if (tt + 1 < ns) LOAD_G(tt + 1);   // refill for next step

        if constexpr (!DEFER) {
            // store out(t-1) — K-loop above read h(t-1)
            int tprev = t0 + tt - 1;
            if (tprev >= 0 && q < 2) {
                int n = w * 16 + lr;
                if (f32m) {
                    float* o32 = (float*)outv;
#pragma unroll
                    for (int r = 0; r < 4; ++r)
                        o32[((size_t)(wg * 8 + q * 4 + r) * 200 + tprev) * 128 + n] = ao[r];
                } else {
                    __hip_bfloat16* o16 = (__hip_bfloat16*)outv;
#pragma unroll
                    for (int r = 0; r < 4; ++r)
                        o16[((size_t)(wg * 8 + q * 4 + r) * 200 + tprev) * 128 + n] = __float2bfloat16(ao[r]);
                }
            }
        }
        LGKM_BARRIER();   // drains h-writes; next step reads the other buffer
    }

    if constexpr (!DEFER) {
        // final chunk: emit out(199) from h(199)
        if (t0 + ns >= 200) {
            const _Float16* __restrict__ hf = h16 + (ns & 1) * 4224;
            floatx4 ao2 = (floatx4){bfc_l, bfc_l, bfc_l, bfc_l};
#pragma unroll
            for (int kt = 0; kt < 8; ++kt) {
                half8 a = *(const half8*)(&hf[lr * 264 + kt * 32 + q * 8]);
                half8 b = Wb[((w * 8) + kt) * 64 + L];
                ao2 = __builtin_amdgcn_mfma_f32_16x16x32_f16(a, b, ao2, 0, 0, 0);
            }
            if (q < 2) {
                int n = w * 16 + lr;
                if (f32m) {
                    float* o32 = (float*)outv;
#pragma unroll
                    for (int r = 0; r < 4; ++r)
                        o32[((size_t)(wg * 8 + q * 4 + r) * 200 + 199) * 128 + n] = ao2[r];
                } else {
                    __hip_bfloat16* o16 = (__hip_bfloat16*)outv;
#pragma unroll
                    for (int r = 0; r < 4; ++r)
                        o16[((size_t)(wg * 8 + q * 4 + r) * 200 + 199) * 128 + n] = __float2bfloat16(ao2[r]);
                }
            }
        }
    }

    // save state (all lanes hold real, disjoint c patches)
    for (int i = tid; i < 8 * 256; i += 512) {
        int m = i >> 8, k = i & 255;
        Hst[(size_t)(wg * 8 + m) * 256 + k] = h16[(ns & 1) * 4224 + m * 264 + k];
    }
    {
        int row = wg * 8 + qe * 4;
#pragma unroll
        for (int r = 0; r < 4; ++r)
            Cst[(size_t)(row + r) * 256 + w * 32 + us * 16 + lr] = creg[r];
    }
#undef LOAD_G
}

// deferred output projection: one WG per t; out[b][t][:] = h(t)[b][:] @ Wfc^T + bfc
__global__ __launch_bounds__(512)
void kout(const float* __restrict__ flag, const _Float16* __restrict__ hall,
          const _Float16* __restrict__ Wfc_sw, const float* __restrict__ can,
          void* __restrict__ outv)
{
    const int t = blockIdx.x;
    const int tid = threadIdx.x;
    __shared__ _Float16 hs[256 * 264];            // 135168 B, padded rows

    const _Float16* __restrict__ hsrc = hall + (size_t)t * 65536;
    for (int i = tid; i < 8192; i += 512) {       // 8192 half8 chunks
        int row = i >> 5, c8 = i & 31;
        *(half8*)&hs[row * 264 + c8 * 8] = *(const half8*)&hsrc[row * 256 + c8 * 8];
    }

    const int w = tid >> 6, L = tid & 63, q = L >> 4, lr = L & 15;
    const half8* __restrict__ Wb = (const half8*)Wfc_sw;
    half8 bw[8];
#pragma unroll
    for (int kt = 0; kt < 8; ++kt)
        bw[kt] = Wb[((w * 8) + kt) * 64 + L];
    const float bfc_l = can[CW_BFC + w * 16 + lr];
    const bool f32m = flag[0] > 0.5f;
    __syncthreads();

    for (int rb = 0; rb < 16; ++rb) {
        floatx4 ao = (floatx4){bfc_l, bfc_l, bfc_l, bfc_l};
#pragma unroll
        for (int kt = 0; kt < 8; ++kt) {
            half8 a = *(const half8*)(&hs[(rb * 16 + lr) * 264 + kt * 32 + q * 8]);
            ao = __builtin_amdgcn_mfma_f32_16x16x32_f16(a, bw[kt], ao, 0, 0, 0);
        }
        int n = w * 16 + lr;
        if (f32m) {
            float* o32 = (float*)outv;
#pragma unroll
            for (int r = 0; r < 4; ++r)
                o32[((size_t)(rb * 16 + q * 4 + r) * 200 + t) * 128 + n] = ao[r];
        } else {
            __hip_bfloat16* o16 = (__hip_bfloat16*)outv;
#pragma unroll
            for (int r = 0; r < 4; ++r)
                o16[((size_t)(rb * 16 + q * 4 + r) * 200 + t) * 128 + n] = __float2bfloat16(ao[r]);
        }
    }
}

extern "C" void kernel_launch(void* const* d_in, const int* in_sizes, int n_in,
                              void* d_out, int out_size, void* d_ws, size_t ws_size,
                              hipStream_t stream)
{
    char* ws = (char*)d_ws;
    float*     flag   = (float*)(ws + OFF_FLAG);
    float*     A32    = (float*)(ws + OFF_A32);
    float*     bq2    = (float*)(ws + OFF_BQ2);
    float*     bfold  = (float*)(ws + OFF_BFOLD);
    float*     can    = (float*)(ws + OFF_CAN);
    _Float16*  U_sw   = (_Float16*)(ws + OFF_USW);
    _Float16*  Wf_sw  = (_Float16*)(ws + OFF_WFSW);
    _Float16*  Wfc_sw = (_Float16*)(ws + OFF_WFCSW);
    _Float16*  Hst    = (_Float16*)(ws + OFF_HST);
    float*     Cst    = (float*)(ws + OFF_CST);

    // chunk schedule + Hall tiering on ws_size.
    const unsigned long long HALL_BYTES = 200ULL * 256 * 256 * 2;  // 26.2 MB
    int t0s[20], nss[20], nch, gcsz;
    bool defer = false;
    if (ws_size >= OFF_GC + 2ULL * 100 * 524288ULL + HALL_BYTES) {
        defer = true;
        nch = 3; gcsz = 100;
        t0s[0] = 0;   nss[0] = 30;
        t0s[1] = 30;  nss[1] = 100;
        t0s[2] = 130; nss[2] = 70;
    } else if (ws_size >= OFF_GC + 2ULL * 100 * 524288ULL) {
        nch = 3; gcsz = 100;
        t0s[0] = 0;   nss[0] = 30;
        t0s[1] = 30;  nss[1] = 100;
        t0s[2] = 130; nss[2] = 70;
    } else {
        int TC = (ws_size >= OFF_GC + 2ULL * 25 * 524288ULL) ? 25 : 12;
        gcsz = TC; nch = 0;
        for (int t0 = 0; t0 < 200; t0 += TC) {
            t0s[nch] = t0;
            nss[nch] = (200 - t0 < TC) ? (200 - t0) : TC;
            ++nch;
        }
    }
    _Float16* Gcb0 = (_Float16*)(ws + OFF_GC);
    _Float16* Gcb1 = Gcb0 + (size_t)gcsz * 262144;
    _Float16* Hall = Gcb1 + (size_t)gcsz * 262144;   // valid only if defer

    hipMemsetAsync(ws + OFF_HST, 0, 0x60000, stream);   // zero h,c state
    kprobe<<<1, 256, 0, stream>>>(d_in[2], flag);
    kconv<<<dim3(320, 16), 256, 0, stream>>>(flag,
        d_in[2], d_in[3], d_in[4], d_in[5], d_in[6], d_in[7],
        d_in[8], d_in[9], d_in[10], d_in[11], d_in[12], d_in[13],
        d_in[14], d_in[15], d_in[16], d_in[17], can);
    k0a<<<65, 256, 0, stream>>>(can, A32, bq2);
    k0b<<<1152, 256, 0, stream>>>(can, A32, bq2, U_sw, Wf_sw, Wfc_sw, bfold);

    // chunk 0 producer (standalone, small)
    k2m<<<4 * nss[0], 512, 0, stream>>>(t0s[0], flag, d_in[0], d_in[1], can,
                                        Wf_sw, bfold, Gcb0);

    for (int c = 0; c < nch; ++c) {
        int nsn = (c + 1 < nch) ? nss[c + 1] : 0;
        int t0n = (c + 1 < nch) ? t0s[c + 1] : 0;
        _Float16* gcur  = (c & 1) ? Gcb1 : Gcb0;
        _Float16* gnext = (c & 1) ? Gcb0 : Gcb1;
        if (defer)
            k3f<true><<<32 + 4 * nsn, 512, 0, stream>>>(t0s[c], nss[c], t0n, flag,
                U_sw, Wfc_sw, can, gcur, gnext, d_in[0], d_in[1], Wf_sw, bfold,
                Hst, Cst, Hall, d_out);
        else
            k3f<false><<<32 + 4 * nsn, 512, 0, stream>>>(t0s[c], nss[c], t0n, flag,
                U_sw, Wfc_sw, can, gcur, gnext, d_in[0], d_in[1], Wf_sw, bfold,
                Hst, Cst, (_Float16*)nullptr, d_out);
    }

    if (defer)
        kout<<<200, 512, 0, stream>>>(flag, Hall, Wfc_sw, can, d_out);
}